// Round 3
// baseline (221.718 us; speedup 1.0000x reference)
//
#include <hip/hip_runtime.h>
#include <climits>
#include <stdint.h>

typedef unsigned int u32;
typedef unsigned long long u64;

#define HH 1536
#define WW 2048
#define NPIX (HH*WW)        // 3145728
#define WSHIFT 11
#define WMASK 2047
#define WPR 64              // words per row (2048/32)
#define TBX 64              // tile cols
#define TBY 48              // tile rows
#define EV (63*1536)        // vertical tile-boundary edges
#define EH (47*2048)        // horizontal tile-boundary edges
#define TCAP 262144
#define RCAP 262144

// ---------------- K1: threshold + pack via ballot ----------------------------
__global__ void k_flags(const float2* __restrict__ xv,
                        u64* __restrict__ combp64, u64* __restrict__ textp64) {
    int gid = blockIdx.x * 256 + threadIdx.x;   // one pixel per lane
    float2 f = xv[gid];
    int tx = f.x > 0.4f;
    int cb = tx | (f.y > 0.4f);
    u64 bc = __ballot(cb);
    u64 bt = __ballot(tx);
    if ((threadIdx.x & 63) == 0) {
        combp64[gid >> 6] = bc;
        textp64[gid >> 6] = bt;
    }
}

// ---------------- helpers ----------------------------------------------------
__device__ __forceinline__ int rstart(u32 m, int c) {
    // start column of the fg run containing bit c (c must be set in m)
    u32 z = ~m & ((1u << c) - 1u);   // zero bits strictly below c
    return z ? (32 - __clz(z)) : 0;
}

__device__ __forceinline__ int lfind(const int* L, int x) {
    int p;
    while ((p = L[x]) != x) x = p;
    return x;
}

__device__ __forceinline__ void lmerge(int* L, int a, int b) {
    while (true) {
        int t;
        while ((t = L[a]) != a) a = t;
        while ((t = L[b]) != b) b = t;
        if (a == b) return;
        if (a < b) { int s = a; a = b; b = s; }
        int old = atomicMin(&L[a], b);
        if (old == a) return;
        a = old;
    }
}

// ---------------- K2: fused dilate + run-based tile CCL + bbox partials ------
// Encodings (identity under any init <= 0, incl. 0xAA poison):
//   ymin_e = 2047 - ymin (>=512), ymax_e = ymax+1, xmin_e = 2048 - xmin (>=1),
//   xmax_e = xmax+1 ; all accumulated with signed atomicMax.
__global__ __launch_bounds__(256) void k_local(
        const u32* __restrict__ combp, const u32* __restrict__ textp,
        u32* __restrict__ fgp, int* __restrict__ labels,
        int* __restrict__ ymin_e, int* __restrict__ xmin_e,
        int* __restrict__ ymax_e, int* __restrict__ xmax_e,
        unsigned char* __restrict__ ht, int* __restrict__ cnt,
        int* __restrict__ tlist) {
    __shared__ u32 hw[34];
    __shared__ u32 fgw[32];
    __shared__ u32 tw[32];
    __shared__ int L[1024];
    __shared__ int shDom;
    __shared__ int sred[4][5];
    int bx = blockIdx.x & (TBX - 1);
    int by = blockIdx.x / TBX;
    int c0 = bx * 32, r0 = by * 32;
    int wq = c0 >> 5;
    int t = threadIdx.x;

    // Phase A: horizontal dilation of comb rows r0-1 .. r0+32
    if (t < 34) {
        int gr = r0 + t - 1;
        u32 m = 0, ml = 0, mr = 0;
        if ((unsigned)gr < (unsigned)HH) {
            int base = gr * WPR;
            m = combp[base + wq];
            ml = (wq > 0)       ? combp[base + wq - 1] : 0u;
            mr = (wq < WPR - 1) ? combp[base + wq + 1] : 0u;
        }
        hw[t] = m | (m << 1) | (ml >> 31) | (m >> 1) | (mr << 31);
    }
    __syncthreads();
    // Phase B: vertical OR -> fg words; stash text words
    if (t < 32) {
        u32 f = hw[t] | hw[t + 1] | hw[t + 2];
        fgw[t] = f;
        fgp[(r0 + t) * WPR + wq] = f;
        tw[t] = textp[(r0 + t) * WPR + wq];
    }
    #pragma unroll
    for (int k = 0; k < 4; ++k) L[t + k * 256] = t + k * 256;
    __syncthreads();

    // Phase C: vertical merges at overlap-segment starts (~1 per row pair)
    if (t < 31) {
        u32 a = fgw[t] & fgw[t + 1];
        u32 starts = a & ~(a << 1);
        while (starts) {
            int c = __ffs(starts) - 1;
            starts &= starts - 1;
            lmerge(L, t * 32 + rstart(fgw[t], c), (t + 1) * 32 + rstart(fgw[t + 1], c));
        }
    }
    __syncthreads();

    // Phase D: dominant local root = root of first fg pixel
    if (t == 0) {
        int dom = -1;
        for (int r = 0; r < 32 && dom < 0; ++r) {
            u32 f = fgw[r];
            if (f) { int c = __ffs(f) - 1; dom = lfind(L, r * 32 + rstart(f, c)); }
        }
        shDom = dom;
    }
    __syncthreads();
    int DOM = shDom;

    // Phase E: per-pixel pass (4 px/thread, conflict-free int LDS access)
    int rmin = INT_MAX, rmax = -1, cmin = INT_MAX, cmax = -1, txt = 0;
    int lc = t & 31;
    #pragma unroll
    for (int k = 0; k < 4; ++k) {
        int li = t + k * 256;
        int lr = li >> 5;
        u32 f = fgw[lr];
        if (!((f >> lc) & 1u)) continue;
        int node = lr * 32 + rstart(f, lc);
        int root = lfind(L, node);
        int tx = (int)((tw[lr] >> lc) & 1u);
        int gi = ((r0 + lr) << WSHIFT) + c0 + lc;
        if (node == li && root == li) {          // tile-local component root
            labels[gi] = gi;
            int idx = atomicAdd(cnt, 1);
            if (idx < TCAP) tlist[idx] = gi;
        } else if (lr == 0 || lr == 31 || lc == 0 || lc == 31) {
            labels[gi] = ((r0 + (root >> 5)) << WSHIFT) + c0 + (root & 31);
        }
        if (root == DOM) {
            rmin = min(rmin, lr); rmax = max(rmax, lr);
            cmin = min(cmin, lc); cmax = max(cmax, lc);
            txt |= tx;
        } else {                                  // rare off-dominant pixel
            int gr = ((r0 + (root >> 5)) << WSHIFT) + c0 + (root & 31);
            atomicMax(&ymin_e[gr], 2047 - (r0 + lr));
            atomicMax(&ymax_e[gr], (r0 + lr) + 1);
            atomicMax(&xmin_e[gr], 2048 - (c0 + lc));
            atomicMax(&xmax_e[gr], (c0 + lc) + 1);
            if (tx) ht[gr] = 1;
        }
    }

    // block reduction for dominant root
    #pragma unroll
    for (int o = 32; o > 0; o >>= 1) {
        rmin = min(rmin, __shfl_xor(rmin, o));
        rmax = max(rmax, __shfl_xor(rmax, o));
        cmin = min(cmin, __shfl_xor(cmin, o));
        cmax = max(cmax, __shfl_xor(cmax, o));
        txt |= __shfl_xor(txt, o);
    }
    int wv = t >> 6;
    if ((t & 63) == 0) {
        sred[wv][0] = rmin; sred[wv][1] = rmax; sred[wv][2] = cmin;
        sred[wv][3] = cmax; sred[wv][4] = txt;
    }
    __syncthreads();
    if (t == 0 && DOM >= 0) {
        for (int w2 = 1; w2 < 4; ++w2) {
            rmin = min(rmin, sred[w2][0]); rmax = max(rmax, sred[w2][1]);
            cmin = min(cmin, sred[w2][2]); cmax = max(cmax, sred[w2][3]);
            txt |= sred[w2][4];
        }
        if (rmax >= 0) {
            int gr = ((r0 + (DOM >> 5)) << WSHIFT) + c0 + (DOM & 31);
            atomicMax(&ymin_e[gr], 2047 - (r0 + rmin));
            atomicMax(&ymax_e[gr], (r0 + rmax) + 1);
            atomicMax(&xmin_e[gr], 2048 - (c0 + cmin));
            atomicMax(&xmax_e[gr], (c0 + cmax) + 1);
            if (txt) ht[gr] = 1;
        }
    }
}

// ---------------- global UF merge (lock-free atomicMin) ----------------------
__device__ __forceinline__ void merge_uf(int* L, int a, int b) {
    while (true) {
        int t;
        while ((t = L[a]) != a) a = t;
        while ((t = L[b]) != b) b = t;
        if (a == b) return;
        if (a < b) { int s = a; a = b; b = s; }
        int old = atomicMin(&L[a], b);
        if (old == a) return;
        a = old;
    }
}

// ---------------- K3: merge across tile boundaries (packed, deduped) ---------
__global__ void k_boundary(int* __restrict__ labels, const u32* __restrict__ fgp) {
    int tid = blockIdx.x * blockDim.x + threadIdx.x;
    if (tid < EV) {                       // vertical edge: (r,c-1)-(r,c), c=32(b+1)
        int b = tid / 1536, r = tid - b * 1536;
        int i = (r << WSHIFT) + (b + 1) * 32;
        u32 wR = fgp[r * WPR + b + 1], wL = fgp[r * WPR + b];
        if (!((wR & 1u) && (wL >> 31))) return;
        if (r & 31) {                     // rungs intra-tile -> dedup
            u32 uR = fgp[(r - 1) * WPR + b + 1], uL = fgp[(r - 1) * WPR + b];
            if ((uR & 1u) && (uL >> 31)) return;
        }
        merge_uf(labels, i, i - 1);
    } else if (tid < EV + EH) {           // horizontal edge: (r-1,c)-(r,c), r=32(bb+1)
        int u = tid - EV;
        int bb = u >> WSHIFT, c = u & WMASK;
        int r = (bb + 1) * 32;
        int i = (r << WSHIFT) + c;
        int w = c >> 5, cb = c & 31;
        u32 wD = fgp[r * WPR + w], wU = fgp[(r - 1) * WPR + w];
        if (!(((wD >> cb) & 1u) && ((wU >> cb) & 1u))) return;
        if (cb) {                         // rungs intra-tile -> dedup
            if (((wD >> (cb - 1)) & 1u) && ((wU >> (cb - 1)) & 1u)) return;
        }
        merge_uf(labels, i, i - WW);
    }
}

// ---------------- find with path halving, minimal stores ---------------------
__device__ __forceinline__ int find_nw(int* L, int i) {
    int x = L[i];
    while (true) {
        int p = L[x];
        if (p == x) return x;
        int gp = L[p];
        if (gp == p) return p;
        L[x] = gp;
        x = gp;
    }
}

// ---------------- K4: fold tile-root partials into global roots --------------
__global__ void k_fold(int* __restrict__ labels,
                       int* __restrict__ ymin_e, int* __restrict__ xmin_e,
                       int* __restrict__ ymax_e, int* __restrict__ xmax_e,
                       unsigned char* __restrict__ ht,
                       const int* __restrict__ cnt, const int* __restrict__ tlist,
                       int* __restrict__ cnt1, int* __restrict__ rlist) {
    int n = min(cnt[0], TCAP);
    for (int i = blockIdx.x * blockDim.x + threadIdx.x; i < n;
         i += gridDim.x * blockDim.x) {
        int tr = tlist[i];
        int R = find_nw(labels, tr);
        if (R != tr) {
            atomicMax(&ymin_e[R], ymin_e[tr]);
            atomicMax(&ymax_e[R], ymax_e[tr]);
            atomicMax(&xmin_e[R], xmin_e[tr]);
            atomicMax(&xmax_e[R], xmax_e[tr]);
            if (ht[tr] == 1) ht[R] = 1;
        } else {
            int idx = atomicAdd(cnt1, 1);
            if (idx < RCAP) rlist[idx] = tr;
        }
    }
}

// ---------------- K5: emit valid roots into zeroed d_out ---------------------
__global__ void k_emit(const int* __restrict__ ymin_e, const int* __restrict__ xmin_e,
                       const int* __restrict__ ymax_e, const int* __restrict__ xmax_e,
                       const unsigned char* __restrict__ ht,
                       const int* __restrict__ cnt1, const int* __restrict__ rlist,
                       int4* __restrict__ obb, int* __restrict__ oval) {
    int n = min(cnt1[0], RCAP);
    for (int i = blockIdx.x * blockDim.x + threadIdx.x; i < n;
         i += gridDim.x * blockDim.x) {
        int R = rlist[i];
        int ym = 2047 - ymin_e[R];
        int yx = ymax_e[R] - 1;
        int xm = 2048 - xmin_e[R];
        int xx = xmax_e[R] - 1;
        int h = yx - ym, w = xx - xm;
        if (h > 4 && w > 4 && ht[R] == 1) {
            obb[R] = make_int4(ym, xm, h, w);
            oval[R] = 1;
        }
    }
}

extern "C" void kernel_launch(void* const* d_in, const int* in_sizes, int n_in,
                              void* d_out, int out_size, void* d_ws, size_t ws_size,
                              hipStream_t stream) {
    const float* x = (const float*)d_in[0];

    // ws layout (labels + 4 encoded bbox arrays rely on 0xAA/0x00 poison as
    // atomicMax identity -> no memset needed for them)
    int* labels  = (int*)d_ws;
    int* ymin_e  = labels + NPIX;
    int* xmin_e  = ymin_e + NPIX;
    int* ymax_e  = xmin_e + NPIX;
    int* xmax_e  = ymax_e + NPIX;
    unsigned char* ht = (unsigned char*)(xmax_e + NPIX);
    u32* combp   = (u32*)(ht + NPIX);
    u32* textp   = combp + NPIX / 32;
    u32* fgp     = textp + NPIX / 32;
    int* cnt     = (int*)(fgp + NPIX / 32);   // cnt[0]=tile roots, cnt[1]=global roots
    int* tlist   = cnt + 2;
    int* rlist   = tlist + TCAP;

    hipMemsetAsync(d_out, 0, (size_t)NPIX * 5 * sizeof(int), stream);
    hipMemsetAsync(cnt, 0, 2 * sizeof(int), stream);

    k_flags<<<NPIX / 256, 256, 0, stream>>>((const float2*)x, (u64*)combp, (u64*)textp);
    k_local<<<TBX * TBY, 256, 0, stream>>>(combp, textp, fgp, labels,
                                           ymin_e, xmin_e, ymax_e, xmax_e,
                                           ht, cnt, tlist);
    k_boundary<<<(EV + EH + 255) / 256, 256, 0, stream>>>(labels, fgp);
    k_fold<<<64, 256, 0, stream>>>(labels, ymin_e, xmin_e, ymax_e, xmax_e,
                                   ht, cnt, tlist, cnt + 1, rlist);

    int* obb  = (int*)d_out;
    int* oval = obb + (size_t)NPIX * 4;
    k_emit<<<16, 256, 0, stream>>>(ymin_e, xmin_e, ymax_e, xmax_e, ht,
                                   cnt + 1, rlist, (int4*)obb, oval);
}